// Round 8
// baseline (264.801 us; speedup 1.0000x reference)
//
#include <hip/hip_runtime.h>
#include <stdint.h>
#include <stddef.h>
#include <math.h>

#define E_ 32
#define H_ 128
#define V_ 32000
#define NB 32
#define NT 128
#define NCONS 224      // consumer blocks (bid 32..255)
#define NCHUNK 250     // 128-col vocab chunks; 224 owned + 26 rotating extras
#define NX (NCHUNK - NCONS)   // 26 extra chunks
#define WSTEPS 16      // pipeline window (steps per release)
#define NWIN (NT / WSTEPS)    // 8 windows

typedef float f32x4 __attribute__((ext_vector_type(4)));
typedef short s16x8 __attribute__((ext_vector_type(8)));

__device__ inline unsigned short f2bf(float f) {
  uint32_t u = __float_as_uint(f);
  return (unsigned short)((u + 0x7FFFu + ((u >> 16) & 1u)) >> 16);
}

__global__ void zero_cnt(int* cnt) {
  if (threadIdx.x < NWIN) cnt[threadIdx.x] = 0;
}

// Fused producer-consumer, grid 256 x 512 (1 block/CU, co-resident).
//  bid 0..31: R6 producer verbatim (known-good).
//  bid 32..255: BARRIER-FREE consumer. No per-step __syncthreads (each one
//    would s_waitcnt vmcnt(0) -> full drain of the step's 16 KB of stores,
//    serializing at ~1.4us/step). Instead each wave loads its own MFMA
//    A-fragments straight from global hbf (L2-served), polls the window flag
//    per-wave, and free-runs; stores drain in the background. Next-step
//    A-loads issue BEFORE this step's stores so the dependent wait is
//    vmcnt(<=12), never a drain.
__global__ __launch_bounds__(512, 1)
void lstm_fused(const float* __restrict__ x,
                const float* __restrict__ Wf, const float* __restrict__ bWf,
                const float* __restrict__ Uf, const float* __restrict__ bUf,
                const float* __restrict__ Wi, const float* __restrict__ bWi,
                const float* __restrict__ Ui, const float* __restrict__ bUi,
                const float* __restrict__ Wc, const float* __restrict__ bWc,
                const float* __restrict__ Uc, const float* __restrict__ bUc,
                const float* __restrict__ Wo, const float* __restrict__ bWo,
                const float* __restrict__ Uo, const float* __restrict__ bUo,
                const float* __restrict__ Vw, const float* __restrict__ Vb,
                unsigned short* __restrict__ hbf,  // [NT][NB][H_] bf16 bits
                int* __restrict__ cnt,             // [NWIN] window counters
                float* __restrict__ out,           // [NB][NT][V_]
                float* __restrict__ hlast)         // [NB][H_]
{
  __shared__ __align__(16) unsigned char smem[65536];
  const int bid = blockIdx.x;
  const int tid = threadIdx.x;

  if (bid < NB) {
    // ---------------- producer: recurrence for batch `bid` (R6 verbatim) ----
    float* xs = reinterpret_cast<float*>(smem);            // [NT][E_] 16 KB
    float* hd = reinterpret_cast<float*>(smem + 16384);    // [2][144] padded h

    const int q  = tid & 3;    // k-quarter
    const int jj = tid >> 2;   // output index 0..127

    const float* WL[4]  = {Wf, Wi, Wc, Wo};
    const float* UL[4]  = {Uf, Ui, Uc, Uo};
    const float* bWL[4] = {bWf, bWi, bWc, bWo};
    const float* bUL[4] = {bUf, bUi, bUc, bUo};

    f32x4 wr_[4][2];  // W[g][jj, 8q..8q+8)
    f32x4 ur_[4][8];  // U[g][jj, 32q..32q+32)  -- 160 VGPRs, MUST NOT SPILL
    float bias_[4];
#pragma unroll
    for (int g = 0; g < 4; ++g) {
      const f32x4* Wp = reinterpret_cast<const f32x4*>(WL[g] + jj * E_ + q * 8);
      wr_[g][0] = Wp[0]; wr_[g][1] = Wp[1];
      const f32x4* Up = reinterpret_cast<const f32x4*>(UL[g] + jj * H_ + q * 32);
#pragma unroll
      for (int r = 0; r < 8; ++r) ur_[g][r] = Up[r];
      bias_[g] = bWL[g][jj] + bUL[g][jj];
    }

    for (int i = tid; i < NT * E_; i += 512) xs[i] = x[bid * (NT * E_) + i];
    if (tid < 144) hd[tid] = 0.f;
    float creg = 0.f;
    __syncthreads();

    for (int t = 0; t < NT; ++t) {
      const int cur = t & 1, nxt = cur ^ 1;
      const f32x4* hq = reinterpret_cast<const f32x4*>(hd + cur * 144 + q * 36);
      const f32x4* xq = reinterpret_cast<const f32x4*>(xs + t * E_ + q * 8);

      f32x4 p0 = {0.f,0.f,0.f,0.f}, p1 = p0, p2 = p0, p3 = p0;
#pragma unroll
      for (int r = 0; r < 2; ++r) {
        f32x4 xv = xq[r];
        p0 += wr_[0][r] * xv; p1 += wr_[1][r] * xv;
        p2 += wr_[2][r] * xv; p3 += wr_[3][r] * xv;
      }
#pragma unroll
      for (int r = 0; r < 8; ++r) {
        f32x4 hv = hq[r];
        p0 += ur_[0][r] * hv; p1 += ur_[1][r] * hv;
        p2 += ur_[2][r] * hv; p3 += ur_[3][r] * hv;
      }
      float s0 = (p0.x + p0.y) + (p0.z + p0.w);
      float s1 = (p1.x + p1.y) + (p1.z + p1.w);
      float s2 = (p2.x + p2.y) + (p2.z + p2.w);
      float s3 = (p3.x + p3.y) + (p3.z + p3.w);
      s0 += __shfl_xor(s0, 1); s0 += __shfl_xor(s0, 2);
      s1 += __shfl_xor(s1, 1); s1 += __shfl_xor(s1, 2);
      s2 += __shfl_xor(s2, 1); s2 += __shfl_xor(s2, 2);
      s3 += __shfl_xor(s3, 1); s3 += __shfl_xor(s3, 2);
      s0 += bias_[0]; s1 += bias_[1]; s2 += bias_[2]; s3 += bias_[3];

      float own = (q == 0) ? s0 : (q == 1) ? s1 : (q == 2) ? s2 : s3;
      float xin = (q == 2) ? own + own : own;
      float sig = 1.f / (1.f + expf(-xin));
      float val = (q == 2) ? 2.f * sig - 1.f : sig;
      float v1 = __shfl_xor(val, 1);
      float v2 = __shfl_xor(val, 2);
      float v3 = __shfl_xor(v1, 2);
      float f_ = (q == 0) ? val : (q == 1) ? v1 : (q == 2) ? v2 : v3;
      float i_ = (q == 0) ? v1 : (q == 1) ? val : (q == 2) ? v3 : v2;
      float c_ = (q == 0) ? v2 : (q == 1) ? v3 : (q == 2) ? val : v1;
      float o_ = (q == 0) ? v3 : (q == 1) ? v2 : (q == 2) ? v1 : val;

      float cn = f_ * creg + i_ * c_;
      creg = cn;
      float hn = o_ * tanhf(cn);

      if (q == 0) {
        hd[nxt * 144 + jj + ((jj >> 5) << 2)] = hn;
        hbf[((size_t)t * NB + bid) * H_ + jj] = f2bf(hn);  // [t][b][H]
        if (t == NT - 1) hlast[bid * H_ + jj] = hn;
      }
      __syncthreads();  // h(t+1) in LDS; all waves' global stores drained
      if ((t & (WSTEPS - 1)) == (WSTEPS - 1) && tid == 0)
        __hip_atomic_fetch_add(&cnt[t / WSTEPS], 1, __ATOMIC_RELEASE,
                               __HIP_MEMORY_SCOPE_AGENT);
    }
    return;
  }

  // ---------------- consumer: own chunk + rotating duty chunk, barrier-free --
  const int cid = bid - NB;                       // 0..223, owns chunk `cid`
  unsigned char* vwo = smem;                      // own  Vw [128][256 B] swizzled
  unsigned char* vwx = smem + 32768;              // duty Vw [128][256 B] swizzled

  const int w = tid >> 6, lane = tid & 63;
  const int wr = w & 1, wc = w >> 1;              // m-tile 0..1, n-32-block 0..3
  const int l15 = lane & 15, lh = lane >> 4;

  // stage own Vw chunk: fp32 -> bf16 -> swizzled LDS (one-time)
  for (int u = tid; u < 2048; u += 512) {         // unit = 8 k-elems of one row
    int n = u >> 4, kc = u & 15;
    const f32x4* src = reinterpret_cast<const f32x4*>(
        Vw + ((size_t)(cid * 128 + n)) * H_ + kc * 8);
    f32x4 a = src[0], b = src[1];
    s16x8 o;
    o[0] = (short)f2bf(a.x); o[1] = (short)f2bf(a.y);
    o[2] = (short)f2bf(a.z); o[3] = (short)f2bf(a.w);
    o[4] = (short)f2bf(b.x); o[5] = (short)f2bf(b.y);
    o[6] = (short)f2bf(b.z); o[7] = (short)f2bf(b.w);
    *reinterpret_cast<s16x8*>(vwo + n * 256 + ((kc * 16) ^ ((n & 7) << 4))) = o;
  }
  float vbo0 = Vb[cid * 128 + wc * 32 + l15];
  float vbo1 = Vb[cid * 128 + wc * 32 + 16 + l15];
  __syncthreads();

  const int ra = wr * 16 + l15;                   // this lane's A row (b index)
  const int akc = lh * 8;                         // this lane's A k-offset

  for (int win = 0; win < NWIN; ++win) {
    // per-wave flag wait: all lanes poll one dword (single request), then
    // one acquire load to invalidate L1 before reading this window's hbf.
    while (__hip_atomic_load(&cnt[win], __ATOMIC_RELAXED,
                             __HIP_MEMORY_SCOPE_AGENT) < NB)
      __builtin_amdgcn_s_sleep(8);
    (void)__hip_atomic_load(&cnt[win], __ATOMIC_ACQUIRE,
                            __HIP_MEMORY_SCOPE_AGENT);

    // rotating duty: window `win` -> blocks 26*win..26*win+25 stage one extra
    const int k = cid - NX * win;
    const bool duty = (k >= 0) && (k < NX);
    int chunk_x = NCONS + k;
    float vbx0 = 0.f, vbx1 = 0.f;
    if (duty) {
      for (int u = tid; u < 2048; u += 512) {
        int n = u >> 4, kc = u & 15;
        const f32x4* src = reinterpret_cast<const f32x4*>(
            Vw + ((size_t)(chunk_x * 128 + n)) * H_ + kc * 8);
        f32x4 a = src[0], b = src[1];
        s16x8 o;
        o[0] = (short)f2bf(a.x); o[1] = (short)f2bf(a.y);
        o[2] = (short)f2bf(a.z); o[3] = (short)f2bf(a.w);
        o[4] = (short)f2bf(b.x); o[5] = (short)f2bf(b.y);
        o[6] = (short)f2bf(b.z); o[7] = (short)f2bf(b.w);
        *reinterpret_cast<s16x8*>(vwx + n * 256 + ((kc * 16) ^ ((n & 7) << 4))) = o;
      }
      vbx0 = Vb[chunk_x * 128 + wc * 32 + l15];
      vbx1 = Vb[chunk_x * 128 + wc * 32 + 16 + l15];
      __syncthreads();  // once per block over the whole kernel (its duty window)
    }

    // A-fragments for step 0 of the window, straight from global
    const int t0 = win * WSTEPS;
    s16x8 af[4];
#pragma unroll
    for (int kt = 0; kt < 4; ++kt)
      af[kt] = *reinterpret_cast<const s16x8*>(
          hbf + ((size_t)t0 * NB + ra) * H_ + kt * 32 + akc);

    for (int tt = 0; tt < WSTEPS; ++tt) {
      const int t = t0 + tt;
      // prefetch next step's A-frags BEFORE this step's stores (vmcnt order)
      s16x8 afn[4];
      if (tt < WSTEPS - 1) {
#pragma unroll
        for (int kt = 0; kt < 4; ++kt)
          afn[kt] = *reinterpret_cast<const s16x8*>(
              hbf + ((size_t)(t + 1) * NB + ra) * H_ + kt * 32 + akc);
      }

      const int rb = wc * 32 + l15;
      // own chunk
      {
        f32x4 acc0 = {0.f,0.f,0.f,0.f}, acc1 = acc0;
#pragma unroll
        for (int kt = 0; kt < 4; ++kt) {
          s16x8 b0 = *reinterpret_cast<const s16x8*>(
              vwo + rb * 256 + ((kt * 64 + lh * 16) ^ ((rb & 7) << 4)));
          s16x8 b1 = *reinterpret_cast<const s16x8*>(
              vwo + (rb + 16) * 256 + ((kt * 64 + lh * 16) ^ (((rb + 16) & 7) << 4)));
          acc0 = __builtin_amdgcn_mfma_f32_16x16x32_bf16(af[kt], b0, acc0, 0, 0, 0);
          acc1 = __builtin_amdgcn_mfma_f32_16x16x32_bf16(af[kt], b1, acc1, 0, 0, 0);
        }
        const int colbase = cid * 128 + wc * 32;
#pragma unroll
        for (int i = 0; i < 4; ++i) {
          int b = wr * 16 + lh * 4 + i;
          float* orow = out + ((size_t)b * NT + t) * V_ + colbase;
          orow[l15]      = acc0[i] + vbo0;
          orow[16 + l15] = acc1[i] + vbo1;
        }
      }
      // duty chunk
      if (duty) {
        f32x4 acc0 = {0.f,0.f,0.f,0.f}, acc1 = acc0;
#pragma unroll
        for (int kt = 0; kt < 4; ++kt) {
          s16x8 b0 = *reinterpret_cast<const s16x8*>(
              vwx + rb * 256 + ((kt * 64 + lh * 16) ^ ((rb & 7) << 4)));
          s16x8 b1 = *reinterpret_cast<const s16x8*>(
              vwx + (rb + 16) * 256 + ((kt * 64 + lh * 16) ^ (((rb + 16) & 7) << 4)));
          acc0 = __builtin_amdgcn_mfma_f32_16x16x32_bf16(af[kt], b0, acc0, 0, 0, 0);
          acc1 = __builtin_amdgcn_mfma_f32_16x16x32_bf16(af[kt], b1, acc1, 0, 0, 0);
        }
        const int colbase = chunk_x * 128 + wc * 32;
#pragma unroll
        for (int i = 0; i < 4; ++i) {
          int b = wr * 16 + lh * 4 + i;
          float* orow = out + ((size_t)b * NT + t) * V_ + colbase;
          orow[l15]      = acc0[i] + vbx0;
          orow[16 + l15] = acc1[i] + vbx1;
        }
      }
      if (tt < WSTEPS - 1) {
#pragma unroll
        for (int kt = 0; kt < 4; ++kt) af[kt] = afn[kt];
      }
    }
  }
}

// ---------------------------------------------------------------------------
extern "C" void kernel_launch(void* const* d_in, const int* in_sizes, int n_in,
                              void* d_out, int out_size, void* d_ws, size_t ws_size,
                              hipStream_t stream) {
  const float* x   = (const float*)d_in[0];
  const float* Wf  = (const float*)d_in[1];
  const float* bWf = (const float*)d_in[2];
  const float* Uf  = (const float*)d_in[3];
  const float* bUf = (const float*)d_in[4];
  const float* Wi  = (const float*)d_in[5];
  const float* bWi = (const float*)d_in[6];
  const float* Ui  = (const float*)d_in[7];
  const float* bUi = (const float*)d_in[8];
  const float* Wc  = (const float*)d_in[9];
  const float* bWc = (const float*)d_in[10];
  const float* Uc  = (const float*)d_in[11];
  const float* bUc = (const float*)d_in[12];
  const float* Wo  = (const float*)d_in[13];
  const float* bWo = (const float*)d_in[14];
  const float* Uo  = (const float*)d_in[15];
  const float* bUo = (const float*)d_in[16];
  const float* Vw  = (const float*)d_in[17];
  const float* Vb  = (const float*)d_in[18];
  float* out = (float*)d_out;

  unsigned short* hbf = (unsigned short*)d_ws;                 // 1 MB [t][b][H]
  int* cnt = (int*)((char*)d_ws + (1u << 20));                 // 32 B
  float* hlast = out + (size_t)NB * NT * V_;

  hipLaunchKernelGGL(zero_cnt, dim3(1), dim3(64), 0, stream, cnt);
  hipLaunchKernelGGL(lstm_fused, dim3(256), dim3(512), 0, stream,
                     x, Wf, bWf, Uf, bUf, Wi, bWi, Ui, bUi, Wc, bWc, Uc, bUc,
                     Wo, bWo, Uo, bUo, Vw, Vb, hbf, cnt, out, hlast);
}

// Round 9
// 246.013 us; speedup vs baseline: 1.0764x; 1.0764x over previous
//
#include <hip/hip_runtime.h>
#include <stdint.h>
#include <stddef.h>
#include <math.h>

#define E_ 32
#define H_ 128
#define V_ 32000
#define NB 32
#define NT 128
#define WSTEPS 16

typedef float f32x4 __attribute__((ext_vector_type(4)));
typedef short s16x8 __attribute__((ext_vector_type(8)));
typedef unsigned short u16x4 __attribute__((ext_vector_type(4)));

__device__ inline unsigned short f2bf(float f) {
  uint32_t u = __float_as_uint(f);
  return (unsigned short)((u + 0x7FFFu + ((u >> 16) & 1u)) >> 16);
}

// ---------------------------------------------------------------------------
// Kernel A: blocks 0..31  -> per-batch LSTM recurrence (fp32, U/W in VGPRs).
//           h buffered in LDS per 16-step window, flushed to hbf once per
//           window -> the per-step __syncthreads waits on LDS only (no global
//           store drain). Activations via __expf + v_rcp (R7-validated).
//           blocks 32..255 -> convert Vw fp32 -> bf16 concurrently.
// ---------------------------------------------------------------------------
__global__ __launch_bounds__(512, 1)
void lstm_rec(const float* __restrict__ x,
              const float* __restrict__ Wf, const float* __restrict__ bWf,
              const float* __restrict__ Uf, const float* __restrict__ bUf,
              const float* __restrict__ Wi, const float* __restrict__ bWi,
              const float* __restrict__ Ui, const float* __restrict__ bUi,
              const float* __restrict__ Wc, const float* __restrict__ bWc,
              const float* __restrict__ Uc, const float* __restrict__ bUc,
              const float* __restrict__ Wo, const float* __restrict__ bWo,
              const float* __restrict__ Uo, const float* __restrict__ bUo,
              const float* __restrict__ Vw,
              unsigned short* __restrict__ hbf,   // [NB][NT][H_] bf16 bits
              unsigned short* __restrict__ vwbf,  // [V_*H_] bf16 bits
              float* __restrict__ hlast)          // d_out tail [NB, H_]
{
  const int bid = blockIdx.x;
  const int tid = threadIdx.x;

  if (bid >= NB) {
    // -------- Vw fp32 -> bf16 conversion (runs concurrently with rec) -------
    const int n4 = V_ * H_ / 4;  // 1,024,000 float4 groups
    for (int i = (bid - NB) * 512 + tid; i < n4; i += (256 - NB) * 512) {
      f32x4 v = *reinterpret_cast<const f32x4*>(Vw + (size_t)i * 4);
      u16x4 o;
      o.x = f2bf(v.x); o.y = f2bf(v.y); o.z = f2bf(v.z); o.w = f2bf(v.w);
      *reinterpret_cast<u16x4*>(vwbf + (size_t)i * 4) = o;
    }
    return;
  }

  // -------- recurrence for batch element `bid` --------
  __shared__ __align__(16) float xs[NT * E_];      // 16 KB
  __shared__ __align__(16) float hd[2 * 144];      // double-buffered h (padded)
  __shared__ __align__(16) float hfl[WSTEPS * H_]; // window h buffer, 8 KB

  const int q  = tid & 3;    // k-quarter
  const int jj = tid >> 2;   // output index 0..127

  const float* WL[4]  = {Wf, Wi, Wc, Wo};
  const float* UL[4]  = {Uf, Ui, Uc, Uo};
  const float* bWL[4] = {bWf, bWi, bWc, bWo};
  const float* bUL[4] = {bUf, bUi, bUc, bUo};

  f32x4 wr_[4][2];  // W[g][jj, 8q..8q+8)
  f32x4 ur_[4][8];  // U[g][jj, 32q..32q+32)  -- 160 VGPRs, must not spill
  float bias_[4];
#pragma unroll
  for (int g = 0; g < 4; ++g) {
    const f32x4* Wp = reinterpret_cast<const f32x4*>(WL[g] + jj * E_ + q * 8);
    wr_[g][0] = Wp[0]; wr_[g][1] = Wp[1];
    const f32x4* Up = reinterpret_cast<const f32x4*>(UL[g] + jj * H_ + q * 32);
#pragma unroll
    for (int r = 0; r < 8; ++r) ur_[g][r] = Up[r];
    bias_[g] = bWL[g][jj] + bUL[g][jj];
  }

  for (int i = tid; i < NT * E_; i += 512) xs[i] = x[bid * (NT * E_) + i];
  if (tid < 144) { hd[tid] = 0.f; hd[144 + tid] = 0.f; }
  float creg = 0.f;
  __syncthreads();

  for (int win = 0; win < NT / WSTEPS; ++win) {
    for (int tt = 0; tt < WSTEPS; ++tt) {
      const int t = win * WSTEPS + tt;
      const int cur = t & 1, nxt = cur ^ 1;
      const f32x4* hq = reinterpret_cast<const f32x4*>(hd + cur * 144 + q * 36);
      const f32x4* xq = reinterpret_cast<const f32x4*>(xs + t * E_ + q * 8);

      f32x4 p0 = {0.f,0.f,0.f,0.f}, p1 = p0, p2 = p0, p3 = p0;
#pragma unroll
      for (int r = 0; r < 2; ++r) {
        f32x4 xv = xq[r];
        p0 += wr_[0][r] * xv; p1 += wr_[1][r] * xv;
        p2 += wr_[2][r] * xv; p3 += wr_[3][r] * xv;
      }
#pragma unroll
      for (int r = 0; r < 8; ++r) {
        f32x4 hv = hq[r];
        p0 += ur_[0][r] * hv; p1 += ur_[1][r] * hv;
        p2 += ur_[2][r] * hv; p3 += ur_[3][r] * hv;
      }
      float s0 = (p0.x + p0.y) + (p0.z + p0.w);
      float s1 = (p1.x + p1.y) + (p1.z + p1.w);
      float s2 = (p2.x + p2.y) + (p2.z + p2.w);
      float s3 = (p3.x + p3.y) + (p3.z + p3.w);
      s0 += __shfl_xor(s0, 1); s0 += __shfl_xor(s0, 2);
      s1 += __shfl_xor(s1, 1); s1 += __shfl_xor(s1, 2);
      s2 += __shfl_xor(s2, 1); s2 += __shfl_xor(s2, 2);
      s3 += __shfl_xor(s3, 1); s3 += __shfl_xor(s3, 2);
      s0 += bias_[0]; s1 += bias_[1]; s2 += bias_[2]; s3 += bias_[3];

      // activation: sigmoid via v_exp+v_rcp; tanh = 2*sigmoid(2x)-1.
      // Validated in R7 (absmax unchanged at 0.00390625).
      float own = (q == 0) ? s0 : (q == 1) ? s1 : (q == 2) ? s2 : s3;
      float xin = (q == 2) ? own + own : own;
      float rv  = __builtin_amdgcn_rcpf(1.f + __expf(-xin));
      float val = (q == 2) ? 2.f * rv - 1.f : rv;
      float v1 = __shfl_xor(val, 1);
      float v2 = __shfl_xor(val, 2);
      float v3 = __shfl_xor(v1, 2);
      float f_ = (q == 0) ? val : (q == 1) ? v1 : (q == 2) ? v2 : v3;
      float i_ = (q == 0) ? v1 : (q == 1) ? val : (q == 2) ? v3 : v2;
      float c_ = (q == 0) ? v2 : (q == 1) ? v3 : (q == 2) ? val : v1;
      float o_ = (q == 0) ? v3 : (q == 1) ? v2 : (q == 2) ? v1 : val;

      float cn = f_ * creg + i_ * c_;
      creg = cn;
      float tn = 2.f * __builtin_amdgcn_rcpf(1.f + __expf(-2.f * cn)) - 1.f;
      float hn = o_ * tn;

      if (q == 0) {
        hd[nxt * 144 + jj + ((jj >> 5) << 2)] = hn;
        hfl[tt * H_ + jj] = hn;
        if (t == NT - 1) hlast[bid * H_ + jj] = hn;
      }
      __syncthreads();  // LDS-only: no global stores queued in the step
    }
    // ---- window flush: hfl[16][128] -> hbf (coalesced 8B/thread) ----
    {
      float f0 = hfl[tid * 4 + 0];
      float f1 = hfl[tid * 4 + 1];
      float f2v = hfl[tid * 4 + 2];
      float f3v = hfl[tid * 4 + 3];
      u16x4 o;
      o.x = f2bf(f0); o.y = f2bf(f1); o.z = f2bf(f2v); o.w = f2bf(f3v);
      u16x4* dst = reinterpret_cast<u16x4*>(
          hbf + ((size_t)bid * NT + win * WSTEPS) * H_);
      dst[tid] = o;
    }
    __syncthreads();  // flush reads done before next window overwrites hfl
  }
}

// ---------------------------------------------------------------------------
// Kernel B: out[4096, 32000] = hbf @ vwbf^T + Vb  (R2-proven, ~90 us)
// 128x128 tile per 256-thread WG; 4 waves in 2x2, each wave 64x64.
// ---------------------------------------------------------------------------
__global__ __launch_bounds__(256, 2)
void vocab_gemm(const unsigned short* __restrict__ hbf,
                const unsigned short* __restrict__ vwbf,
                const float* __restrict__ Vb,
                float* __restrict__ out)
{
  __shared__ __align__(16) unsigned char As[128 * 256];  // 32 KB
  __shared__ __align__(16) unsigned char Bs[128 * 256];  // 32 KB

  const int tid = threadIdx.x;
  const int ntile = blockIdx.x;  // 0..249
  const int mtile = blockIdx.y;  // 0..31

  const unsigned char* Ag = reinterpret_cast<const unsigned char*>(hbf) + (size_t)mtile * 128 * 256;
  const unsigned char* Bg = reinterpret_cast<const unsigned char*>(vwbf) + (size_t)ntile * 128 * 256;

#pragma unroll
  for (int it = 0; it < 8; ++it) {
    int L = it * 4096 + tid * 16;
    int row = L >> 8;
    int sw = (row & 7) << 4;
    int src = (L & ~255) | ((L & 255) ^ sw);
    *reinterpret_cast<f32x4*>(&As[L]) = *reinterpret_cast<const f32x4*>(Ag + src);
    *reinterpret_cast<f32x4*>(&Bs[L]) = *reinterpret_cast<const f32x4*>(Bg + src);
  }
  __syncthreads();

  const int lane = tid & 63;
  const int w = tid >> 6;
  const int wr = w >> 1, wc = w & 1;
  const int l15 = lane & 15, lh = lane >> 4;

  f32x4 acc[4][4];
#pragma unroll
  for (int mt = 0; mt < 4; ++mt)
#pragma unroll
    for (int nt = 0; nt < 4; ++nt)
      acc[mt][nt] = (f32x4){0.f, 0.f, 0.f, 0.f};

#pragma unroll
  for (int kt = 0; kt < 4; ++kt) {
    const int cb = kt * 64 + lh * 16;
    s16x8 af[4], bfr[4];
#pragma unroll
    for (int mt = 0; mt < 4; ++mt) {
      int ra = wr * 64 + mt * 16 + l15;
      af[mt] = *reinterpret_cast<const s16x8*>(&As[ra * 256 + (cb ^ ((ra & 7) << 4))]);
      int rb = wc * 64 + mt * 16 + l15;
      bfr[mt] = *reinterpret_cast<const s16x8*>(&Bs[rb * 256 + (cb ^ ((rb & 7) << 4))]);
    }
#pragma unroll
    for (int mt = 0; mt < 4; ++mt)
#pragma unroll
      for (int nt = 0; nt < 4; ++nt)
        acc[mt][nt] = __builtin_amdgcn_mfma_f32_16x16x32_bf16(af[mt], bfr[nt], acc[mt][nt], 0, 0, 0);
  }

  float vb[4];
#pragma unroll
  for (int nt = 0; nt < 4; ++nt)
    vb[nt] = Vb[ntile * 128 + wc * 64 + nt * 16 + l15];

#pragma unroll
  for (int mt = 0; mt < 4; ++mt) {
#pragma unroll
    for (int i = 0; i < 4; ++i) {
      int rrow = mtile * 128 + wr * 64 + mt * 16 + lh * 4 + i;
      float* orow = out + (size_t)rrow * V_ + ntile * 128 + wc * 64;
#pragma unroll
      for (int nt = 0; nt < 4; ++nt)
        orow[nt * 16 + l15] = acc[mt][nt][i] + vb[nt];
    }
  }
}

// ---------------------------------------------------------------------------
extern "C" void kernel_launch(void* const* d_in, const int* in_sizes, int n_in,
                              void* d_out, int out_size, void* d_ws, size_t ws_size,
                              hipStream_t stream) {
  const float* x   = (const float*)d_in[0];
  const float* Wf  = (const float*)d_in[1];
  const float* bWf = (const float*)d_in[2];
  const float* Uf  = (const float*)d_in[3];
  const float* bUf = (const float*)d_in[4];
  const float* Wi  = (const float*)d_in[5];
  const float* bWi = (const float*)d_in[6];
  const float* Ui  = (const float*)d_in[7];
  const float* bUi = (const float*)d_in[8];
  const float* Wc  = (const float*)d_in[9];
  const float* bWc = (const float*)d_in[10];
  const float* Uc  = (const float*)d_in[11];
  const float* bUc = (const float*)d_in[12];
  const float* Wo  = (const float*)d_in[13];
  const float* bWo = (const float*)d_in[14];
  const float* Uo  = (const float*)d_in[15];
  const float* bUo = (const float*)d_in[16];
  const float* Vw  = (const float*)d_in[17];
  const float* Vb  = (const float*)d_in[18];
  float* out = (float*)d_out;

  unsigned short* hbf  = (unsigned short*)d_ws;                       // 1 MB
  unsigned short* vwbf = (unsigned short*)((char*)d_ws + (1u << 20)); // 8.2 MB
  float* hlast = out + (size_t)NB * NT * V_;

  hipLaunchKernelGGL(lstm_rec, dim3(256), dim3(512), 0, stream,
                     x, Wf, bWf, Uf, bUf, Wi, bWi, Ui, bUi, Wc, bWc, Uc, bUc,
                     Wo, bWo, Uo, bUo, Vw, hbf, vwbf, hlast);
  hipLaunchKernelGGL(vocab_gemm, dim3(V_ / 128, (NB * NT) / 128), dim3(256), 0, stream,
                     hbf, vwbf, Vb, out);
}

// Round 10
// 166.315 us; speedup vs baseline: 1.5922x; 1.4792x over previous
//
#include <hip/hip_runtime.h>
#include <stdint.h>
#include <stddef.h>
#include <math.h>

#define E_ 32
#define H_ 128
#define V_ 32000
#define NB 32
#define NT 128
#define NCONS 224      // consumer blocks (bid 32..255)
#define NCHUNK 250     // 128-col vocab chunks; 224 owned + 26 rotating extras
#define NX (NCHUNK - NCONS)   // 26 extra chunks
#define WSTEPS 16      // pipeline window (steps per release)
#define NWIN (NT / WSTEPS)    // 8 windows

typedef float f32x4 __attribute__((ext_vector_type(4)));
typedef short s16x8 __attribute__((ext_vector_type(8)));

__device__ inline unsigned short f2bf(float f) {
  uint32_t u = __float_as_uint(f);
  return (unsigned short)((u + 0x7FFFu + ((u >> 16) & 1u)) >> 16);
}

// Intra-quad exchanges as DPP quad_perm (VALU, 2 cyc, zero LDS issue).
// __shfl_xor on CDNA lowers to ds_swizzle (an LDS instruction, ~5.8 cyc and
// contends with the h/x ds_reads on the single LDS issue port) — the
// producer's 11 shuffles/step were ~510 cyc/step of LDS pressure.
__device__ inline float dpp_xor1(float v) {   // lane l <- lane l^1
  return __int_as_float(__builtin_amdgcn_update_dpp(
      0, __float_as_int(v), 0xB1 /*quad_perm[1,0,3,2]*/, 0xF, 0xF, true));
}
__device__ inline float dpp_xor2(float v) {   // lane l <- lane l^2
  return __int_as_float(__builtin_amdgcn_update_dpp(
      0, __float_as_int(v), 0x4E /*quad_perm[2,3,0,1]*/, 0xF, 0xF, true));
}

__global__ void zero_cnt(int* cnt) {
  if (threadIdx.x < NWIN) cnt[threadIdx.x] = 0;
}

// Fused producer-consumer, grid 256 x 512 (1 block/CU, all co-resident).
// Structure identical to the measured-190.8us R6 kernel; producer-only deltas:
// DPP instead of ds_swizzle shuffles, __expf+v_rcp instead of expf/tanhf
// libcalls (formula bit-validated in R7: absmax unchanged).
__global__ __launch_bounds__(512, 1)
void lstm_fused(const float* __restrict__ x,
                const float* __restrict__ Wf, const float* __restrict__ bWf,
                const float* __restrict__ Uf, const float* __restrict__ bUf,
                const float* __restrict__ Wi, const float* __restrict__ bWi,
                const float* __restrict__ Ui, const float* __restrict__ bUi,
                const float* __restrict__ Wc, const float* __restrict__ bWc,
                const float* __restrict__ Uc, const float* __restrict__ bUc,
                const float* __restrict__ Wo, const float* __restrict__ bWo,
                const float* __restrict__ Uo, const float* __restrict__ bUo,
                const float* __restrict__ Vw, const float* __restrict__ Vb,
                unsigned short* __restrict__ hbf,  // [NT][NB][H_] bf16 bits
                int* __restrict__ cnt,             // [NWIN] window counters
                float* __restrict__ out,           // [NB][NT][V_]
                float* __restrict__ hlast)         // [NB][H_]
{
  __shared__ __align__(16) unsigned char smem[81920];
  const int bid = blockIdx.x;
  const int tid = threadIdx.x;

  if (bid < NB) {
    // ---------------- producer: recurrence for batch `bid` ----------------
    float* xs = reinterpret_cast<float*>(smem);            // [NT][E_] 16 KB
    float* hd = reinterpret_cast<float*>(smem + 16384);    // [2][144] padded h

    const int q  = tid & 3;    // k-quarter
    const int jj = tid >> 2;   // output index 0..127

    const float* WL[4]  = {Wf, Wi, Wc, Wo};
    const float* UL[4]  = {Uf, Ui, Uc, Uo};
    const float* bWL[4] = {bWf, bWi, bWc, bWo};
    const float* bUL[4] = {bUf, bUi, bUc, bUo};

    f32x4 wr_[4][2];  // W[g][jj, 8q..8q+8)
    f32x4 ur_[4][8];  // U[g][jj, 32q..32q+32)  -- 160 VGPRs, MUST NOT SPILL
    float bias_[4];
#pragma unroll
    for (int g = 0; g < 4; ++g) {
      const f32x4* Wp = reinterpret_cast<const f32x4*>(WL[g] + jj * E_ + q * 8);
      wr_[g][0] = Wp[0]; wr_[g][1] = Wp[1];
      const f32x4* Up = reinterpret_cast<const f32x4*>(UL[g] + jj * H_ + q * 32);
#pragma unroll
      for (int r = 0; r < 8; ++r) ur_[g][r] = Up[r];
      bias_[g] = bWL[g][jj] + bUL[g][jj];
    }

    for (int i = tid; i < NT * E_; i += 512) xs[i] = x[bid * (NT * E_) + i];
    if (tid < 144) hd[tid] = 0.f;
    float creg = 0.f;
    __syncthreads();

    for (int t = 0; t < NT; ++t) {
      const int cur = t & 1, nxt = cur ^ 1;
      const f32x4* hq = reinterpret_cast<const f32x4*>(hd + cur * 144 + q * 36);
      const f32x4* xq = reinterpret_cast<const f32x4*>(xs + t * E_ + q * 8);

      f32x4 p0 = {0.f,0.f,0.f,0.f}, p1 = p0, p2 = p0, p3 = p0;
#pragma unroll
      for (int r = 0; r < 2; ++r) {
        f32x4 xv = xq[r];
        p0 += wr_[0][r] * xv; p1 += wr_[1][r] * xv;
        p2 += wr_[2][r] * xv; p3 += wr_[3][r] * xv;
      }
#pragma unroll
      for (int r = 0; r < 8; ++r) {
        f32x4 hv = hq[r];
        p0 += ur_[0][r] * hv; p1 += ur_[1][r] * hv;
        p2 += ur_[2][r] * hv; p3 += ur_[3][r] * hv;
      }
      float s0 = (p0.x + p0.y) + (p0.z + p0.w);
      float s1 = (p1.x + p1.y) + (p1.z + p1.w);
      float s2 = (p2.x + p2.y) + (p2.z + p2.w);
      float s3 = (p3.x + p3.y) + (p3.z + p3.w);
      // quad tree-reduce over k-quarters (DPP, VALU-only)
      s0 += dpp_xor1(s0); s0 += dpp_xor2(s0);
      s1 += dpp_xor1(s1); s1 += dpp_xor2(s1);
      s2 += dpp_xor1(s2); s2 += dpp_xor2(s2);
      s3 += dpp_xor1(s3); s3 += dpp_xor2(s3);
      s0 += bias_[0]; s1 += bias_[1]; s2 += bias_[2]; s3 += bias_[3];

      // lane q activates gate q; sigmoid via __expf+v_rcp, tanh = 2σ(2x)-1
      // (R7-validated: absmax identical 0.00390625)
      float own = (q == 0) ? s0 : (q == 1) ? s1 : (q == 2) ? s2 : s3;
      float xin = (q == 2) ? own + own : own;
      float val = __builtin_amdgcn_rcpf(1.f + __expf(-xin));
      if (q == 2) val = 2.f * val - 1.f;
      // quad all-gather of the 4 activations (DPP)
      float v1 = dpp_xor1(val);
      float v2 = dpp_xor2(val);
      float v3 = dpp_xor2(v1);
      float f_ = (q == 0) ? val : (q == 1) ? v1 : (q == 2) ? v2 : v3;
      float i_ = (q == 0) ? v1 : (q == 1) ? val : (q == 2) ? v3 : v2;
      float c_ = (q == 0) ? v2 : (q == 1) ? v3 : (q == 2) ? val : v1;
      float o_ = (q == 0) ? v3 : (q == 1) ? v2 : (q == 2) ? v1 : val;

      float cn = f_ * creg + i_ * c_;
      creg = cn;
      float hn = o_ * (2.f * __builtin_amdgcn_rcpf(1.f + __expf(-2.f * cn)) - 1.f);

      if (q == 0) {
        hd[nxt * 144 + jj + ((jj >> 5) << 2)] = hn;
        hbf[((size_t)t * NB + bid) * H_ + jj] = f2bf(hn);  // [t][b][H]
        if (t == NT - 1) hlast[bid * H_ + jj] = hn;
      }
      __syncthreads();  // h(t+1) in LDS; all waves' global stores drained
      if ((t & (WSTEPS - 1)) == (WSTEPS - 1) && tid == 0)
        __hip_atomic_fetch_add(&cnt[t / WSTEPS], 1, __ATOMIC_RELEASE,
                               __HIP_MEMORY_SCOPE_AGENT);
    }
    return;
  }

  // ---------------- consumer: own chunk + rotating duty chunk (R6 verbatim) --
  const int cid = bid - NB;                       // 0..223, owns chunk `cid`
  unsigned char* vwo = smem;                      // own  Vw [128][256 B] swizzled
  unsigned char* vwx = smem + 32768;              // duty Vw [128][256 B] swizzled
  unsigned char* hlb = smem + 65536;              // [2][32 rows][256 B] swizzled

  const int w = tid >> 6, lane = tid & 63;
  const int wr = w & 1, wc = w >> 1;              // m-tile 0..1, n-32-block 0..3
  const int l15 = lane & 15, lh = lane >> 4;

  // stage own Vw chunk: fp32 -> bf16 -> swizzled LDS (one-time)
  for (int u = tid; u < 2048; u += 512) {         // unit = 8 k-elems of one row
    int n = u >> 4, kc = u & 15;
    const f32x4* src = reinterpret_cast<const f32x4*>(
        Vw + ((size_t)(cid * 128 + n)) * H_ + kc * 8);
    f32x4 a = src[0], b = src[1];
    s16x8 o;
    o[0] = (short)f2bf(a.x); o[1] = (short)f2bf(a.y);
    o[2] = (short)f2bf(a.z); o[3] = (short)f2bf(a.w);
    o[4] = (short)f2bf(b.x); o[5] = (short)f2bf(b.y);
    o[6] = (short)f2bf(b.z); o[7] = (short)f2bf(b.w);
    *reinterpret_cast<s16x8*>(vwo + n * 256 + ((kc * 16) ^ ((n & 7) << 4))) = o;
  }
  float vbo0 = Vb[cid * 128 + wc * 32 + l15];
  float vbo1 = Vb[cid * 128 + wc * 32 + 16 + l15];
  const int hb_ = tid >> 4, hkc_ = tid & 15;      // h-stage LDS slot for this thread
  const int hswz = hb_ * 256 + ((hkc_ * 16) ^ ((hb_ & 7) << 4));
  __syncthreads();

  for (int win = 0; win < NWIN; ++win) {
    if (tid == 0) {
      while (__hip_atomic_load(&cnt[win], __ATOMIC_RELAXED,
                               __HIP_MEMORY_SCOPE_AGENT) < NB)
        __builtin_amdgcn_s_sleep(8);
      (void)__hip_atomic_load(&cnt[win], __ATOMIC_ACQUIRE,
                              __HIP_MEMORY_SCOPE_AGENT);  // one L1/L2 invalidate
    }
    __syncthreads();

    // prefetch h for this window's step 0 (drains under duty staging)
    s16x8 hv = *reinterpret_cast<const s16x8*>(
        hbf + (size_t)(win * WSTEPS) * (NB * H_) + tid * 8);

    // rotating duty: in window `win`, blocks 26*win .. 26*win+25 stage one
    // extra chunk each. Every (chunk,window) covered exactly once.
    const int k = cid - NX * win;
    const bool duty = (k >= 0) && (k < NX);
    int chunk_x = NCONS + k;
    float vbx0 = 0.f, vbx1 = 0.f;
    if (duty) {
      for (int u = tid; u < 2048; u += 512) {
        int n = u >> 4, kc = u & 15;
        const f32x4* src = reinterpret_cast<const f32x4*>(
            Vw + ((size_t)(chunk_x * 128 + n)) * H_ + kc * 8);
        f32x4 a = src[0], b = src[1];
        s16x8 o;
        o[0] = (short)f2bf(a.x); o[1] = (short)f2bf(a.y);
        o[2] = (short)f2bf(a.z); o[3] = (short)f2bf(a.w);
        o[4] = (short)f2bf(b.x); o[5] = (short)f2bf(b.y);
        o[6] = (short)f2bf(b.z); o[7] = (short)f2bf(b.w);
        *reinterpret_cast<s16x8*>(vwx + n * 256 + ((kc * 16) ^ ((n & 7) << 4))) = o;
      }
      vbx0 = Vb[chunk_x * 128 + wc * 32 + l15];
      vbx1 = Vb[chunk_x * 128 + wc * 32 + 16 + l15];
    }
    // duty ds_writes become visible at the first step's post-stage barrier.

    for (int tt = 0; tt < WSTEPS; ++tt) {
      const int t = win * WSTEPS + tt;
      unsigned char* hcur = hlb + (tt & 1) * 8192;
      // write prefetched h_t to LDS, then immediately issue the load for t+1
      // (it stays in flight across the barrier, consumed next step)
      *reinterpret_cast<s16x8*>(hcur + hswz) = hv;
      if (tt < WSTEPS - 1)
        hv = *reinterpret_cast<const s16x8*>(
            hbf + (size_t)(t + 1) * (NB * H_) + tid * 8);
      __syncthreads();

      s16x8 af[4];
      const int ra = wr * 16 + l15;
#pragma unroll
      for (int kt = 0; kt < 4; ++kt)
        af[kt] = *reinterpret_cast<const s16x8*>(
            hcur + ra * 256 + ((kt * 64 + lh * 16) ^ ((ra & 7) << 4)));

      const int rb = wc * 32 + l15;
      // own chunk
      {
        f32x4 acc0 = {0.f,0.f,0.f,0.f}, acc1 = acc0;
#pragma unroll
        for (int kt = 0; kt < 4; ++kt) {
          s16x8 b0 = *reinterpret_cast<const s16x8*>(
              vwo + rb * 256 + ((kt * 64 + lh * 16) ^ ((rb & 7) << 4)));
          s16x8 b1 = *reinterpret_cast<const s16x8*>(
              vwo + (rb + 16) * 256 + ((kt * 64 + lh * 16) ^ (((rb + 16) & 7) << 4)));
          acc0 = __builtin_amdgcn_mfma_f32_16x16x32_bf16(af[kt], b0, acc0, 0, 0, 0);
          acc1 = __builtin_amdgcn_mfma_f32_16x16x32_bf16(af[kt], b1, acc1, 0, 0, 0);
        }
        const int colbase = cid * 128 + wc * 32;
#pragma unroll
        for (int i = 0; i < 4; ++i) {
          int b = wr * 16 + lh * 4 + i;
          float* orow = out + ((size_t)b * NT + t) * V_ + colbase;
          orow[l15]      = acc0[i] + vbo0;
          orow[16 + l15] = acc1[i] + vbo1;
        }
      }
      // duty chunk
      if (duty) {
        f32x4 acc0 = {0.f,0.f,0.f,0.f}, acc1 = acc0;
#pragma unroll
        for (int kt = 0; kt < 4; ++kt) {
          s16x8 b0 = *reinterpret_cast<const s16x8*>(
              vwx + rb * 256 + ((kt * 64 + lh * 16) ^ ((rb & 7) << 4)));
          s16x8 b1 = *reinterpret_cast<const s16x8*>(
              vwx + (rb + 16) * 256 + ((kt * 64 + lh * 16) ^ (((rb + 16) & 7) << 4)));
          acc0 = __builtin_amdgcn_mfma_f32_16x16x32_bf16(af[kt], b0, acc0, 0, 0, 0);
          acc1 = __builtin_amdgcn_mfma_f32_16x16x32_bf16(af[kt], b1, acc1, 0, 0, 0);
        }
        const int colbase = chunk_x * 128 + wc * 32;
#pragma unroll
        for (int i = 0; i < 4; ++i) {
          int b = wr * 16 + lh * 4 + i;
          float* orow = out + ((size_t)b * NT + t) * V_ + colbase;
          orow[l15]      = acc0[i] + vbx0;
          orow[16 + l15] = acc1[i] + vbx1;
        }
      }
    }
  }
}

// ---------------------------------------------------------------------------
extern "C" void kernel_launch(void* const* d_in, const int* in_sizes, int n_in,
                              void* d_out, int out_size, void* d_ws, size_t ws_size,
                              hipStream_t stream) {
  const float* x   = (const float*)d_in[0];
  const float* Wf  = (const float*)d_in[1];
  const float* bWf = (const float*)d_in[2];
  const float* Uf  = (const float*)d_in[3];
  const float* bUf = (const float*)d_in[4];
  const float* Wi  = (const float*)d_in[5];
  const float* bWi = (const float*)d_in[6];
  const float* Ui  = (const float*)d_in[7];
  const float* bUi = (const float*)d_in[8];
  const float* Wc  = (const float*)d_in[9];
  const float* bWc = (const float*)d_in[10];
  const float* Uc  = (const float*)d_in[11];
  const float* bUc = (const float*)d_in[12];
  const float* Wo  = (const float*)d_in[13];
  const float* bWo = (const float*)d_in[14];
  const float* Uo  = (const float*)d_in[15];
  const float* bUo = (const float*)d_in[16];
  const float* Vw  = (const float*)d_in[17];
  const float* Vb  = (const float*)d_in[18];
  float* out = (float*)d_out;

  unsigned short* hbf = (unsigned short*)d_ws;                 // 1 MB [t][b][H]
  int* cnt = (int*)((char*)d_ws + (1u << 20));                 // 32 B
  float* hlast = out + (size_t)NB * NT * V_;

  hipLaunchKernelGGL(zero_cnt, dim3(1), dim3(64), 0, stream, cnt);
  hipLaunchKernelGGL(lstm_fused, dim3(256), dim3(512), 0, stream,
                     x, Wf, bWf, Uf, bUf, Wi, bWi, Ui, bUi, Wc, bWc, Uc, bUc,
                     Wo, bWo, Uo, bUo, Vw, Vb, hbf, cnt, out, hlast);
}